// Round 2
// baseline (3029.616 us; speedup 1.0000x reference)
//
#include <hip/hip_runtime.h>
#include <stdint.h>

#define D 128
#define EPW 8  // edges per wave in k_agg

__device__ __forceinline__ float bf16_lo(uint32_t u) { return __uint_as_float(u << 16); }
__device__ __forceinline__ float bf16_hi(uint32_t u) { return __uint_as_float(u & 0xffff0000u); }
__device__ __forceinline__ uint16_t f32_to_bf16(float f) {
    uint32_t u = __float_as_uint(f);
    uint32_t r = u + 0x7fffu + ((u >> 16) & 1u);  // round-to-nearest-even
    return (uint16_t)(r >> 16);
}

// Transpose+scale weights into bf16: WtS[i*128+o] = bf16(0.5f * W_src[o*128+i])
// Combined bias: bias[o] = 0.5*(b_src[o] + b_dst[o])  (fp32)
__global__ __launch_bounds__(256) void k_prep_w(
    const float* __restrict__ Wsrc, const float* __restrict__ bsrc,
    const float* __restrict__ Wdst, const float* __restrict__ bdst,
    uint16_t* __restrict__ WtS, uint16_t* __restrict__ WtD, float* __restrict__ bias)
{
    int t = blockIdx.x * 256 + threadIdx.x;  // 0..32767
    if (t < 16384) {
        int o = t & 127, i = t >> 7;
        WtS[i * 128 + o] = f32_to_bf16(0.5f * Wsrc[o * 128 + i]);
        if (t < 128) bias[t] = 0.5f * (bsrc[t] + bdst[t]);
    } else {
        int t2 = t - 16384;
        int o = t2 & 127, i = t2 >> 7;
        WtD[i * 128 + o] = f32_to_bf16(0.5f * Wdst[o * 128 + i]);
    }
}

__global__ __launch_bounds__(256) void k_deg(
    const int* __restrict__ ei, int E,
    uint32_t* __restrict__ deg_out, uint32_t* __restrict__ deg_in)
{
    int e = blockIdx.x * 256 + threadIdx.x;
    if (e < E) {
        atomicAdd(&deg_out[ei[e]], 1u);
        atomicAdd(&deg_in[ei[E + e]], 1u);
    }
}

__global__ __launch_bounds__(256) void k_inv(
    const uint32_t* __restrict__ deg_out, const uint32_t* __restrict__ deg_in,
    float* __restrict__ inv_out, float* __restrict__ inv_in, int N)
{
    int t = blockIdx.x * 256 + threadIdx.x;
    if (t < N) {
        uint32_t a = deg_out[t];
        uint32_t b = deg_in[t];
        inv_out[t] = a ? rsqrtf((float)a) : 0.0f;
        inv_in[t]  = b ? rsqrtf((float)b) : 0.0f;
    }
}

// One wave per EPW edges. Lane l handles feature elements 2l, 2l+1 (float2).
__global__ __launch_bounds__(256) void k_agg(
    const float2* __restrict__ x2,  // x rows as float2, stride 64
    const int* __restrict__ ei, int E,
    const float* __restrict__ inv_out, const float* __restrict__ inv_in,
    float* __restrict__ aggf, float* __restrict__ aggb)
{
    int lane = threadIdx.x & 63;
    long wid = (long)blockIdx.x * 4 + (threadIdx.x >> 6);
    long e0 = wid * EPW;
    for (int k = 0; k < EPW; ++k) {
        long e = e0 + k;
        if (e >= E) return;
        int row = ei[e];
        int col = ei[E + e];
        float w = inv_out[row] * inv_in[col];
        float2 xc = x2[(long)col * 64 + lane];
        float2 xr = x2[(long)row * 64 + lane];
        float* pf = aggf + (long)row * 128 + 2 * lane;
        atomicAdd(pf,     w * xc.x);
        atomicAdd(pf + 1, w * xc.y);
        float* pb = aggb + (long)col * 128 + 2 * lane;
        atomicAdd(pb,     w * xr.x);
        atomicAdd(pb + 1, w * xr.y);
    }
}

// out[n,o] = sum_i aggf[n,i]*WtS[i,o] + aggb[n,i]*WtD[i,o] + bias[o]
// (alpha folded into WtS/WtD/bias). One wave handles 2 nodes; lane owns outputs 2l, 2l+1.
__global__ __launch_bounds__(256) void k_gemm(
    const float* __restrict__ aggf, const float* __restrict__ aggb,
    const uint16_t* __restrict__ WtS, const uint16_t* __restrict__ WtD,
    const float* __restrict__ bias, float2* __restrict__ out, int N, int npairs)
{
    __shared__ uint32_t sWs[8192];  // [i][o-pair] bf16x2, 32 KB
    __shared__ uint32_t sWd[8192];
    const uint32_t* gWs = (const uint32_t*)WtS;
    const uint32_t* gWd = (const uint32_t*)WtD;
    for (int j = threadIdx.x; j < 8192; j += 256) {
        sWs[j] = gWs[j];
        sWd[j] = gWd[j];
    }
    __syncthreads();

    int lane = threadIdx.x & 63;
    int wid = blockIdx.x * 4 + (threadIdx.x >> 6);
    int nw = gridDim.x * 4;
    float b0 = bias[2 * lane];
    float b1 = bias[2 * lane + 1];

    for (int p = wid; p < npairs; p += nw) {
        int n0 = 2 * p;
        int n1 = n0 + 1;
        bool has1 = (n1 < N);
        const float* af0 = aggf + (long)n0 * 128;
        const float* ab0 = aggb + (long)n0 * 128;
        const float* af1 = has1 ? (aggf + (long)n1 * 128) : af0;
        const float* ab1 = has1 ? (aggb + (long)n1 * 128) : ab0;
        float acc00 = b0, acc01 = b1, acc10 = b0, acc11 = b1;
        #pragma unroll 8
        for (int i = 0; i < 128; ++i) {
            uint32_t uws = sWs[i * 64 + lane];
            uint32_t uwd = sWd[i * 64 + lane];
            float ws0 = bf16_lo(uws), ws1 = bf16_hi(uws);
            float wd0 = bf16_lo(uwd), wd1 = bf16_hi(uwd);
            float a0 = af0[i], c0 = ab0[i];
            float a1 = af1[i], c1 = ab1[i];
            acc00 += a0 * ws0 + c0 * wd0;
            acc01 += a0 * ws1 + c0 * wd1;
            acc10 += a1 * ws0 + c1 * wd0;
            acc11 += a1 * ws1 + c1 * wd1;
        }
        out[(long)n0 * 64 + lane] = make_float2(acc00, acc01);
        if (has1)
            out[(long)n1 * 64 + lane] = make_float2(acc10, acc11);
    }
}

extern "C" void kernel_launch(void* const* d_in, const int* in_sizes, int n_in,
                              void* d_out, int out_size, void* d_ws, size_t ws_size,
                              hipStream_t stream) {
    const int N = in_sizes[0] / D;   // 100000
    const int E = in_sizes[1] / 2;   // 1600000

    const float* x    = (const float*)d_in[0];
    const int*   ei   = (const int*)d_in[1];
    const float* Wsrc = (const float*)d_in[2];
    const float* bsrc = (const float*)d_in[3];
    const float* Wdst = (const float*)d_in[4];
    const float* bdst = (const float*)d_in[5];

    char* ws = (char*)d_ws;
    size_t off = 0;
    uint32_t* deg_out = (uint32_t*)(ws + off); off += (size_t)N * 4;
    uint32_t* deg_in  = (uint32_t*)(ws + off); off += (size_t)N * 4;
    float*    aggf    = (float*)(ws + off);    off += (size_t)N * D * 4;
    float*    aggb    = (float*)(ws + off);    off += (size_t)N * D * 4;
    size_t zero_bytes = off;                   // degrees + accumulators need zeroing
    float*    inv_out = (float*)(ws + off);    off += (size_t)N * 4;
    float*    inv_in  = (float*)(ws + off);    off += (size_t)N * 4;
    uint16_t* WtS     = (uint16_t*)(ws + off); off += (size_t)D * D * 2;
    uint16_t* WtD     = (uint16_t*)(ws + off); off += (size_t)D * D * 2;
    float*    biasc   = (float*)(ws + off);    off += (size_t)D * 4;

    hipMemsetAsync(d_ws, 0, zero_bytes, stream);

    k_prep_w<<<128, 256, 0, stream>>>(Wsrc, bsrc, Wdst, bdst, WtS, WtD, biasc);

    k_deg<<<(E + 255) / 256, 256, 0, stream>>>(ei, E, deg_out, deg_in);

    k_inv<<<(N + 255) / 256, 256, 0, stream>>>(deg_out, deg_in, inv_out, inv_in, N);

    int agg_blocks = (E + 4 * EPW - 1) / (4 * EPW);
    k_agg<<<agg_blocks, 256, 0, stream>>>((const float2*)x, ei, E, inv_out, inv_in, aggf, aggb);

    int npairs = (N + 1) / 2;
    k_gemm<<<1024, 256, 0, stream>>>(aggf, aggb, WtS, WtD, biasc, (float2*)d_out, N, npairs);
}

// Round 3
// 797.981 us; speedup vs baseline: 3.7966x; 3.7966x over previous
//
#include <hip/hip_runtime.h>
#include <stdint.h>

#define D 128

__device__ __forceinline__ float bf16_lo(uint32_t u) { return __uint_as_float(u << 16); }
__device__ __forceinline__ float bf16_hi(uint32_t u) { return __uint_as_float(u & 0xffff0000u); }
__device__ __forceinline__ uint16_t f32_to_bf16(float f) {
    uint32_t u = __float_as_uint(f);
    uint32_t r = u + 0x7fffu + ((u >> 16) & 1u);  // round-to-nearest-even
    return (uint16_t)(r >> 16);
}
__device__ __forceinline__ uint32_t pack2(float a, float b) {
    return (uint32_t)f32_to_bf16(a) | ((uint32_t)f32_to_bf16(b) << 16);
}

// Transpose+scale weights into bf16: WtS[i*128+o] = bf16(0.5f * W_src[o*128+i])
// Combined bias: bias[o] = 0.5*(b_src[o] + b_dst[o])  (fp32)
__global__ __launch_bounds__(256) void k_prep_w(
    const float* __restrict__ Wsrc, const float* __restrict__ bsrc,
    const float* __restrict__ Wdst, const float* __restrict__ bdst,
    uint16_t* __restrict__ WtS, uint16_t* __restrict__ WtD, float* __restrict__ bias)
{
    int t = blockIdx.x * 256 + threadIdx.x;  // 0..32767
    if (t < 16384) {
        int o = t & 127, i = t >> 7;
        WtS[i * 128 + o] = f32_to_bf16(0.5f * Wsrc[o * 128 + i]);
        if (t < 128) bias[t] = 0.5f * (bsrc[t] + bdst[t]);
    } else {
        int t2 = t - 16384;
        int o = t2 & 127, i = t2 >> 7;
        WtD[i * 128 + o] = f32_to_bf16(0.5f * Wdst[o * 128 + i]);
    }
}

// Degree histogram into concatenated array: dcat[0..N)=deg_out, dcat[N..2N)=deg_in
__global__ __launch_bounds__(256) void k_deg(
    const int* __restrict__ ei, int E, int N, uint32_t* __restrict__ dcat)
{
    int e = blockIdx.x * 256 + threadIdx.x;
    if (e < E) {
        atomicAdd(&dcat[ei[e]], 1u);
        atomicAdd(&dcat[N + ei[E + e]], 1u);
    }
}

// ---- 3-kernel exclusive scan over dcat[0..M) -> ptr (positions into edata) ----
// scan1: per-block (1024 elems) local exclusive scan + block sum
__global__ __launch_bounds__(256) void k_scan1(
    const uint32_t* __restrict__ d, uint32_t* __restrict__ ps,
    uint32_t* __restrict__ bsum, int M)
{
    __shared__ uint32_t s[256];
    int base = blockIdx.x * 1024 + threadIdx.x * 4;
    uint32_t v0 = (base + 0 < M) ? d[base + 0] : 0u;
    uint32_t v1 = (base + 1 < M) ? d[base + 1] : 0u;
    uint32_t v2 = (base + 2 < M) ? d[base + 2] : 0u;
    uint32_t v3 = (base + 3 < M) ? d[base + 3] : 0u;
    uint32_t tsum = v0 + v1 + v2 + v3;
    s[threadIdx.x] = tsum;
    __syncthreads();
    for (int off = 1; off < 256; off <<= 1) {
        uint32_t t = (threadIdx.x >= (unsigned)off) ? s[threadIdx.x - off] : 0u;
        __syncthreads();
        s[threadIdx.x] += t;
        __syncthreads();
    }
    uint32_t excl = s[threadIdx.x] - tsum;
    if (threadIdx.x == 255) bsum[blockIdx.x] = s[255];
    if (base + 0 < M) ps[base + 0] = excl;
    if (base + 1 < M) ps[base + 1] = excl + v0;
    if (base + 2 < M) ps[base + 2] = excl + v0 + v1;
    if (base + 3 < M) ps[base + 3] = excl + v0 + v1 + v2;
}

// scan2: single block exclusive-scans the block sums (NB <= 256)
__global__ __launch_bounds__(256) void k_scan2(uint32_t* __restrict__ bsum, int NB)
{
    __shared__ uint32_t s[256];
    uint32_t v = (threadIdx.x < (unsigned)NB) ? bsum[threadIdx.x] : 0u;
    s[threadIdx.x] = v;
    __syncthreads();
    for (int off = 1; off < 256; off <<= 1) {
        uint32_t t = (threadIdx.x >= (unsigned)off) ? s[threadIdx.x - off] : 0u;
        __syncthreads();
        s[threadIdx.x] += t;
        __syncthreads();
    }
    if (threadIdx.x < (unsigned)NB) bsum[threadIdx.x] = s[threadIdx.x] - v;
}

// scan3: add block offsets; write final ptr AND a working copy (cursor) for the fill
__global__ __launch_bounds__(256) void k_scan3(
    uint32_t* __restrict__ ps, uint32_t* __restrict__ cursor,
    const uint32_t* __restrict__ bsum, int M)
{
    int base = blockIdx.x * 1024 + threadIdx.x * 4;
    uint32_t off = bsum[blockIdx.x];
    #pragma unroll
    for (int j = 0; j < 4; ++j) {
        int i = base + j;
        if (i < M) {
            uint32_t v = ps[i] + off;
            ps[i] = v;
            cursor[i] = v;
        }
    }
}

__global__ __launch_bounds__(256) void k_inv(
    const uint32_t* __restrict__ dcat,
    float* __restrict__ inv_out, float* __restrict__ inv_in, int N)
{
    int t = blockIdx.x * 256 + threadIdx.x;
    if (t < N) {
        uint32_t a = dcat[t];
        uint32_t b = dcat[N + t];
        inv_out[t] = a ? rsqrtf((float)a) : 0.0f;
        inv_in[t]  = b ? rsqrtf((float)b) : 0.0f;
    }
}

// Bucket fill: CSR cols in edata[0..E) segments, CSC rows in edata[E..2E) segments
// (cursor[N+c] already includes the +E offset via the concatenated scan)
__global__ __launch_bounds__(256) void k_fill(
    const int* __restrict__ ei, int E, int N,
    uint32_t* __restrict__ cursor, int* __restrict__ edata)
{
    int e = blockIdx.x * 256 + threadIdx.x;
    if (e < E) {
        int r = ei[e];
        int c = ei[E + e];
        uint32_t p1 = atomicAdd(&cursor[r], 1u);
        edata[p1] = c;
        uint32_t p2 = atomicAdd(&cursor[N + c], 1u);
        edata[p2] = r;
    }
}

// u[n] = inv_in[n] * (x[n] @ WtS)   (alpha folded into WtS)   -> bf16x2 packed
// v[n] = inv_out[n] * (x[n] @ WtD)                             -> bf16x2 packed
// One wave handles 2 nodes; lane owns outputs 2l, 2l+1.
__global__ __launch_bounds__(256) void k_uv(
    const float* __restrict__ x,
    const uint16_t* __restrict__ WtS, const uint16_t* __restrict__ WtD,
    const float* __restrict__ inv_out, const float* __restrict__ inv_in,
    uint32_t* __restrict__ u2, uint32_t* __restrict__ v2, int N, int npairs)
{
    __shared__ uint32_t sWs[8192];  // [i][o-pair] bf16x2, 32 KB
    __shared__ uint32_t sWd[8192];
    const uint32_t* gWs = (const uint32_t*)WtS;
    const uint32_t* gWd = (const uint32_t*)WtD;
    for (int j = threadIdx.x; j < 8192; j += 256) {
        sWs[j] = gWs[j];
        sWd[j] = gWd[j];
    }
    __syncthreads();

    int lane = threadIdx.x & 63;
    int wid = blockIdx.x * 4 + (threadIdx.x >> 6);
    int nw = gridDim.x * 4;

    for (int p = wid; p < npairs; p += nw) {
        int n0 = 2 * p;
        int n1 = n0 + 1;
        bool has1 = (n1 < N);
        const float* xr0 = x + (long)n0 * 128;
        const float* xr1 = has1 ? (x + (long)n1 * 128) : xr0;
        float au00 = 0, au01 = 0, av00 = 0, av01 = 0;
        float au10 = 0, au11 = 0, av10 = 0, av11 = 0;
        #pragma unroll 8
        for (int i = 0; i < 128; ++i) {
            uint32_t uws = sWs[i * 64 + lane];
            uint32_t uwd = sWd[i * 64 + lane];
            float ws0 = bf16_lo(uws), ws1 = bf16_hi(uws);
            float wd0 = bf16_lo(uwd), wd1 = bf16_hi(uwd);
            float x0 = xr0[i], x1 = xr1[i];
            au00 += x0 * ws0; au01 += x0 * ws1;
            av00 += x0 * wd0; av01 += x0 * wd1;
            au10 += x1 * ws0; au11 += x1 * ws1;
            av10 += x1 * wd0; av11 += x1 * wd1;
        }
        float ii0 = inv_in[n0], io0 = inv_out[n0];
        u2[(long)n0 * 64 + lane] = pack2(ii0 * au00, ii0 * au01);
        v2[(long)n0 * 64 + lane] = pack2(io0 * av00, io0 * av01);
        if (has1) {
            float ii1 = inv_in[n1], io1 = inv_out[n1];
            u2[(long)n1 * 64 + lane] = pack2(ii1 * au10, ii1 * au11);
            v2[(long)n1 * 64 + lane] = pack2(io1 * av10, io1 * av11);
        }
    }
}

// One wave per node: out[n] = inv_out[n]*sum(u[CSR cols]) + inv_in[n]*sum(v[CSC rows]) + bias
__global__ __launch_bounds__(256) void k_gather(
    const uint32_t* __restrict__ u2, const uint32_t* __restrict__ v2,
    const int* __restrict__ edata,
    const uint32_t* __restrict__ ptr, const uint32_t* __restrict__ dcat,
    const float* __restrict__ inv_out, const float* __restrict__ inv_in,
    const float2* __restrict__ bias2, float2* __restrict__ out2, int N)
{
    int lane = threadIdx.x & 63;
    int node = blockIdx.x * 4 + (threadIdx.x >> 6);
    if (node >= N) return;

    uint32_t s0 = ptr[node],      d0 = dcat[node];       // CSR segment (out-edges)
    uint32_t s1 = ptr[N + node],  d1 = dcat[N + node];   // CSC segment (in-edges)

    float fx = 0, fy = 0, bx = 0, by = 0;
    uint32_t k = 0;
    for (; k + 4 <= d0; k += 4) {
        int c0 = edata[s0 + k], c1 = edata[s0 + k + 1];
        int c2 = edata[s0 + k + 2], c3 = edata[s0 + k + 3];
        uint32_t p0 = u2[(long)c0 * 64 + lane];
        uint32_t p1 = u2[(long)c1 * 64 + lane];
        uint32_t p2 = u2[(long)c2 * 64 + lane];
        uint32_t p3 = u2[(long)c3 * 64 + lane];
        fx += bf16_lo(p0) + bf16_lo(p1) + bf16_lo(p2) + bf16_lo(p3);
        fy += bf16_hi(p0) + bf16_hi(p1) + bf16_hi(p2) + bf16_hi(p3);
    }
    for (; k < d0; ++k) {
        uint32_t p = u2[(long)edata[s0 + k] * 64 + lane];
        fx += bf16_lo(p); fy += bf16_hi(p);
    }
    k = 0;
    for (; k + 4 <= d1; k += 4) {
        int c0 = edata[s1 + k], c1 = edata[s1 + k + 1];
        int c2 = edata[s1 + k + 2], c3 = edata[s1 + k + 3];
        uint32_t p0 = v2[(long)c0 * 64 + lane];
        uint32_t p1 = v2[(long)c1 * 64 + lane];
        uint32_t p2 = v2[(long)c2 * 64 + lane];
        uint32_t p3 = v2[(long)c3 * 64 + lane];
        bx += bf16_lo(p0) + bf16_lo(p1) + bf16_lo(p2) + bf16_lo(p3);
        by += bf16_hi(p0) + bf16_hi(p1) + bf16_hi(p2) + bf16_hi(p3);
    }
    for (; k < d1; ++k) {
        uint32_t p = v2[(long)edata[s1 + k] * 64 + lane];
        bx += bf16_lo(p); by += bf16_hi(p);
    }

    float io = inv_out[node], ii = inv_in[node];
    float2 b = bias2[lane];
    out2[(long)node * 64 + lane] =
        make_float2(io * fx + ii * bx + b.x, io * fy + ii * by + b.y);
}

extern "C" void kernel_launch(void* const* d_in, const int* in_sizes, int n_in,
                              void* d_out, int out_size, void* d_ws, size_t ws_size,
                              hipStream_t stream) {
    const int N = in_sizes[0] / D;   // 100000
    const int E = in_sizes[1] / 2;   // 1600000
    const int M = 2 * N;
    const int NB = (M + 1023) / 1024;  // 196 <= 256 (k_scan2 capacity)

    const float* x    = (const float*)d_in[0];
    const int*   ei   = (const int*)d_in[1];
    const float* Wsrc = (const float*)d_in[2];
    const float* bsrc = (const float*)d_in[3];
    const float* Wdst = (const float*)d_in[4];
    const float* bdst = (const float*)d_in[5];

    char* ws = (char*)d_ws;
    size_t off = 0;
    uint32_t* dcat   = (uint32_t*)(ws + off); off += (size_t)M * 4;      // zeroed
    uint32_t* ptr    = (uint32_t*)(ws + off); off += (size_t)M * 4;
    uint32_t* cursor = (uint32_t*)(ws + off); off += (size_t)M * 4;
    uint32_t* bsum   = (uint32_t*)(ws + off); off += 1024 * 4;
    float*    inv_o  = (float*)(ws + off);    off += (size_t)N * 4;
    float*    inv_i  = (float*)(ws + off);    off += (size_t)N * 4;
    float*    biasc  = (float*)(ws + off);    off += 128 * 4;
    uint16_t* WtS    = (uint16_t*)(ws + off); off += (size_t)D * D * 2;
    uint16_t* WtD    = (uint16_t*)(ws + off); off += (size_t)D * D * 2;
    int*      edata  = (int*)(ws + off);      off += (size_t)2 * E * 4;
    uint32_t* u2     = (uint32_t*)(ws + off); off += (size_t)N * 64 * 4;
    uint32_t* v2     = (uint32_t*)(ws + off); off += (size_t)N * 64 * 4;

    hipMemsetAsync(dcat, 0, (size_t)M * 4, stream);

    k_prep_w<<<128, 256, 0, stream>>>(Wsrc, bsrc, Wdst, bdst, WtS, WtD, biasc);
    k_deg<<<(E + 255) / 256, 256, 0, stream>>>(ei, E, N, dcat);
    k_scan1<<<NB, 256, 0, stream>>>(dcat, ptr, bsum, M);
    k_scan2<<<1, 256, 0, stream>>>(bsum, NB);
    k_scan3<<<NB, 256, 0, stream>>>(ptr, cursor, bsum, M);
    k_inv<<<(N + 255) / 256, 256, 0, stream>>>(dcat, inv_o, inv_i, N);
    k_fill<<<(E + 255) / 256, 256, 0, stream>>>(ei, E, N, cursor, edata);

    int npairs = (N + 1) / 2;
    k_uv<<<1024, 256, 0, stream>>>(x, WtS, WtD, inv_o, inv_i, u2, v2, N, npairs);

    k_gather<<<(N + 3) / 4, 256, 0, stream>>>(u2, v2, edata, ptr, dcat,
                                              inv_o, inv_i, (const float2*)biasc,
                                              (float2*)d_out, N);
}

// Round 4
// 485.570 us; speedup vs baseline: 6.2393x; 1.6434x over previous
//
#include <hip/hip_runtime.h>
#include <stdint.h>

#define D 128
#define CC 4096   // edges per k_count block
#define CE 2048   // edges per k_part block (4096 entries in LDS)

__device__ __forceinline__ float bf16_lo(uint32_t u) { return __uint_as_float(u << 16); }
__device__ __forceinline__ float bf16_hi(uint32_t u) { return __uint_as_float(u & 0xffff0000u); }
__device__ __forceinline__ uint16_t f32_to_bf16(float f) {
    uint32_t u = __float_as_uint(f);
    uint32_t r = u + 0x7fffu + ((u >> 16) & 1u);  // round-to-nearest-even
    return (uint16_t)(r >> 16);
}
__device__ __forceinline__ uint32_t pack2(float a, float b) {
    return (uint32_t)f32_to_bf16(a) | ((uint32_t)f32_to_bf16(b) << 16);
}

// Transpose+scale weights into bf16: WtS[i*128+o] = bf16(0.5f * W_src[o*128+i])
__global__ __launch_bounds__(256) void k_prep_w(
    const float* __restrict__ Wsrc, const float* __restrict__ bsrc,
    const float* __restrict__ Wdst, const float* __restrict__ bdst,
    uint16_t* __restrict__ WtS, uint16_t* __restrict__ WtD, float* __restrict__ bias)
{
    int t = blockIdx.x * 256 + threadIdx.x;  // 0..32767
    if (t < 16384) {
        int o = t & 127, i = t >> 7;
        WtS[i * 128 + o] = f32_to_bf16(0.5f * Wsrc[o * 128 + i]);
        if (t < 128) bias[t] = 0.5f * (bsrc[t] + bdst[t]);
    } else {
        int t2 = t - 16384;
        int o = t2 & 127, i = t2 >> 7;
        WtD[i * 128 + o] = f32_to_bf16(0.5f * Wdst[o * 128 + i]);
    }
}

// Coarse bucket counts. bucket = node>>8; fwd buckets [0,nbuk), bwd [nbuk,2*nbuk)
__global__ __launch_bounds__(256) void k_count(
    const int* __restrict__ ei, int E, int nbuk, uint32_t* __restrict__ gcount)
{
    __shared__ uint32_t cnt[1024];
    int nb2 = 2 * nbuk;
    for (int j = threadIdx.x; j < nb2; j += 256) cnt[j] = 0;
    __syncthreads();
    int base = blockIdx.x * CC;
    int lim = min(CC, E - base);
    for (int i = threadIdx.x; i < lim; i += 256) {
        int r = ei[base + i];
        int c = ei[E + base + i];
        atomicAdd(&cnt[r >> 8], 1u);
        atomicAdd(&cnt[nbuk + (c >> 8)], 1u);
    }
    __syncthreads();
    for (int j = threadIdx.x; j < nb2; j += 256) {
        uint32_t v = cnt[j];
        if (v) atomicAdd(&gcount[j], v);
    }
}

// Exclusive scan of gcount[0..nb2) -> pbase; gcursor = copy (mutable)
__global__ __launch_bounds__(256) void k_bases(
    const uint32_t* __restrict__ gcount, uint32_t* __restrict__ pbase,
    uint32_t* __restrict__ gcursor, int nb2)
{
    __shared__ uint32_t s[256];
    uint32_t v[4]; uint32_t tsum = 0;
    int b0 = threadIdx.x * 4;
    #pragma unroll
    for (int j = 0; j < 4; ++j) { v[j] = (b0 + j < nb2) ? gcount[b0 + j] : 0u; tsum += v[j]; }
    s[threadIdx.x] = tsum;
    __syncthreads();
    for (int off = 1; off < 256; off <<= 1) {
        uint32_t t = (threadIdx.x >= (unsigned)off) ? s[threadIdx.x - off] : 0u;
        __syncthreads();
        s[threadIdx.x] += t;
        __syncthreads();
    }
    uint32_t run = s[threadIdx.x] - tsum;
    #pragma unroll
    for (int j = 0; j < 4; ++j) {
        if (b0 + j < nb2) { pbase[b0 + j] = run; gcursor[b0 + j] = run; }
        run += v[j];
    }
}

// Partition: block counting-sorts its 2048 edges (x2 dirs) by coarse bucket in LDS,
// reserves per-bucket global runs, streams bucket-sorted entries out (coalesced).
// Entry pack: (payload << 8) | (key & 255)   (payload < 2^17, fits 25 bits)
__global__ __launch_bounds__(256) void k_part(
    const int* __restrict__ ei, int E, int nbuk,
    uint32_t* __restrict__ gcursor, uint32_t* __restrict__ gpairs)
{
    __shared__ uint32_t cnt[1024];
    __shared__ uint32_t loff[1024];
    __shared__ uint32_t gbase[1024];
    __shared__ uint32_t spair[2 * CE];
    __shared__ uint16_t sbid[2 * CE];
    __shared__ uint32_t ssum[256];
    int nb2 = 2 * nbuk;
    for (int j = threadIdx.x; j < nb2; j += 256) cnt[j] = 0;
    __syncthreads();
    int base = blockIdx.x * CE;
    int lim = min(CE, E - base);
    // pass 1: count
    for (int i = threadIdx.x; i < lim; i += 256) {
        int r = ei[base + i];
        int c = ei[E + base + i];
        atomicAdd(&cnt[r >> 8], 1u);
        atomicAdd(&cnt[nbuk + (c >> 8)], 1u);
    }
    __syncthreads();
    // exclusive scan cnt -> loff (thread t handles [4t, 4t+4))
    uint32_t v0 = 0, v1 = 0, v2 = 0, v3 = 0;
    int b0 = threadIdx.x * 4;
    if (b0 < nb2)     v0 = cnt[b0];
    if (b0 + 1 < nb2) v1 = cnt[b0 + 1];
    if (b0 + 2 < nb2) v2 = cnt[b0 + 2];
    if (b0 + 3 < nb2) v3 = cnt[b0 + 3];
    uint32_t tsum = v0 + v1 + v2 + v3;
    ssum[threadIdx.x] = tsum;
    __syncthreads();
    for (int off = 1; off < 256; off <<= 1) {
        uint32_t t = (threadIdx.x >= (unsigned)off) ? ssum[threadIdx.x - off] : 0u;
        __syncthreads();
        ssum[threadIdx.x] += t;
        __syncthreads();
    }
    uint32_t run = ssum[threadIdx.x] - tsum;
    if (b0 < nb2)     loff[b0]     = run;
    if (b0 + 1 < nb2) loff[b0 + 1] = run + v0;
    if (b0 + 2 < nb2) loff[b0 + 2] = run + v0 + v1;
    if (b0 + 3 < nb2) loff[b0 + 3] = run + v0 + v1 + v2;
    __syncthreads();
    // reserve global runs; repurpose cnt as scatter cursor
    for (int j = threadIdx.x; j < nb2; j += 256) {
        uint32_t c2 = cnt[j];
        gbase[j] = c2 ? atomicAdd(&gcursor[j], c2) : 0u;
        cnt[j] = loff[j];
    }
    __syncthreads();
    // pass 2: scatter into LDS (bucket-sorted)
    for (int i = threadIdx.x; i < lim; i += 256) {
        int r = ei[base + i];
        int c = ei[E + base + i];
        int bf = r >> 8;
        uint32_t sf = atomicAdd(&cnt[bf], 1u);
        spair[sf] = ((uint32_t)c << 8) | (uint32_t)(r & 255);
        sbid[sf] = (uint16_t)bf;
        int bb = nbuk + (c >> 8);
        uint32_t sb = atomicAdd(&cnt[bb], 1u);
        spair[sb] = ((uint32_t)r << 8) | (uint32_t)(c & 255);
        sbid[sb] = (uint16_t)bb;
    }
    __syncthreads();
    // pass 3: linear write-out, coalesced within runs
    int total = 2 * lim;
    for (int s2 = threadIdx.x; s2 < total; s2 += 256) {
        int b = sbid[s2];
        gpairs[gbase[b] + ((uint32_t)s2 - loff[b])] = spair[s2];
    }
}

// Fine build: one block per (dir,bucket). Histogram of 256 local keys, scan,
// write ptr/deg/inv (coalesced), scatter payloads into the bucket's hot edata region.
__global__ __launch_bounds__(256) void k_build(
    const uint32_t* __restrict__ gpairs, const uint32_t* __restrict__ pbase,
    const uint32_t* __restrict__ gcount, int nbuk, int N,
    int* __restrict__ edata, uint32_t* __restrict__ ptrg, uint32_t* __restrict__ degg,
    float* __restrict__ inv_o, float* __restrict__ inv_i)
{
    __shared__ uint32_t hist[256], cur[256], ssum[256];
    int b = blockIdx.x;
    int dir = (b >= nbuk) ? 1 : 0;
    int node0 = (b - dir * nbuk) << 8;
    uint32_t base = pbase[b];
    uint32_t cnt_b = gcount[b];
    hist[threadIdx.x] = 0;
    __syncthreads();
    for (uint32_t i = threadIdx.x; i < cnt_b; i += 256)
        atomicAdd(&hist[gpairs[base + i] & 255u], 1u);
    __syncthreads();
    uint32_t h = hist[threadIdx.x];
    ssum[threadIdx.x] = h;
    __syncthreads();
    for (int off = 1; off < 256; off <<= 1) {
        uint32_t t = (threadIdx.x >= (unsigned)off) ? ssum[threadIdx.x - off] : 0u;
        __syncthreads();
        ssum[threadIdx.x] += t;
        __syncthreads();
    }
    uint32_t excl = ssum[threadIdx.x] - h;
    cur[threadIdx.x] = excl;
    int n = node0 + threadIdx.x;
    if (n < N) {
        ptrg[dir * N + n] = base + excl;
        degg[dir * N + n] = h;
        float iv = h ? rsqrtf((float)h) : 0.0f;
        if (dir == 0) inv_o[n] = iv; else inv_i[n] = iv;
    }
    __syncthreads();
    for (uint32_t i = threadIdx.x; i < cnt_b; i += 256) {
        uint32_t e = gpairs[base + i];
        uint32_t pos = atomicAdd(&cur[e & 255u], 1u);
        edata[base + pos] = (int)(e >> 8);
    }
}

// u[n] = inv_in[n] * (x[n] @ WtS)  -> bf16x2 ;  v[n] = inv_out[n] * (x[n] @ WtD)
__global__ __launch_bounds__(256) void k_uv(
    const float* __restrict__ x,
    const uint16_t* __restrict__ WtS, const uint16_t* __restrict__ WtD,
    const float* __restrict__ inv_out, const float* __restrict__ inv_in,
    uint32_t* __restrict__ u2, uint32_t* __restrict__ v2, int N, int npairs)
{
    __shared__ uint32_t sWs[8192];  // [i][o-pair] bf16x2, 32 KB
    __shared__ uint32_t sWd[8192];
    const uint32_t* gWs = (const uint32_t*)WtS;
    const uint32_t* gWd = (const uint32_t*)WtD;
    for (int j = threadIdx.x; j < 8192; j += 256) {
        sWs[j] = gWs[j];
        sWd[j] = gWd[j];
    }
    __syncthreads();

    int lane = threadIdx.x & 63;
    int wid = blockIdx.x * 4 + (threadIdx.x >> 6);
    int nw = gridDim.x * 4;

    for (int p = wid; p < npairs; p += nw) {
        int n0 = 2 * p;
        int n1 = n0 + 1;
        bool has1 = (n1 < N);
        const float* xr0 = x + (long)n0 * 128;
        const float* xr1 = has1 ? (x + (long)n1 * 128) : xr0;
        float au00 = 0, au01 = 0, av00 = 0, av01 = 0;
        float au10 = 0, au11 = 0, av10 = 0, av11 = 0;
        #pragma unroll 8
        for (int i = 0; i < 128; ++i) {
            uint32_t uws = sWs[i * 64 + lane];
            uint32_t uwd = sWd[i * 64 + lane];
            float ws0 = bf16_lo(uws), ws1 = bf16_hi(uws);
            float wd0 = bf16_lo(uwd), wd1 = bf16_hi(uwd);
            float x0 = xr0[i], x1 = xr1[i];
            au00 += x0 * ws0; au01 += x0 * ws1;
            av00 += x0 * wd0; av01 += x0 * wd1;
            au10 += x1 * ws0; au11 += x1 * ws1;
            av10 += x1 * wd0; av11 += x1 * wd1;
        }
        float ii0 = inv_in[n0], io0 = inv_out[n0];
        u2[(long)n0 * 64 + lane] = pack2(ii0 * au00, ii0 * au01);
        v2[(long)n0 * 64 + lane] = pack2(io0 * av00, io0 * av01);
        if (has1) {
            float ii1 = inv_in[n1], io1 = inv_out[n1];
            u2[(long)n1 * 64 + lane] = pack2(ii1 * au10, ii1 * au11);
            v2[(long)n1 * 64 + lane] = pack2(io1 * av10, io1 * av11);
        }
    }
}

// One wave per node: out[n] = inv_out[n]*sum(u[CSR cols]) + inv_in[n]*sum(v[CSC rows]) + bias
__global__ __launch_bounds__(256) void k_gather(
    const uint32_t* __restrict__ u2, const uint32_t* __restrict__ v2,
    const int* __restrict__ edata,
    const uint32_t* __restrict__ ptrg, const uint32_t* __restrict__ degg,
    const float* __restrict__ inv_out, const float* __restrict__ inv_in,
    const float2* __restrict__ bias2, float2* __restrict__ out2, int N)
{
    int lane = threadIdx.x & 63;
    int node = blockIdx.x * 4 + (threadIdx.x >> 6);
    if (node >= N) return;

    uint32_t s0 = ptrg[node],     d0 = degg[node];       // CSR segment (out-edges)
    uint32_t s1 = ptrg[N + node], d1 = degg[N + node];   // CSC segment (in-edges)

    float fx = 0, fy = 0, bx = 0, by = 0;
    uint32_t k = 0;
    for (; k + 4 <= d0; k += 4) {
        int c0 = edata[s0 + k], c1 = edata[s0 + k + 1];
        int c2 = edata[s0 + k + 2], c3 = edata[s0 + k + 3];
        uint32_t p0 = u2[(long)c0 * 64 + lane];
        uint32_t p1 = u2[(long)c1 * 64 + lane];
        uint32_t p2 = u2[(long)c2 * 64 + lane];
        uint32_t p3 = u2[(long)c3 * 64 + lane];
        fx += bf16_lo(p0) + bf16_lo(p1) + bf16_lo(p2) + bf16_lo(p3);
        fy += bf16_hi(p0) + bf16_hi(p1) + bf16_hi(p2) + bf16_hi(p3);
    }
    for (; k < d0; ++k) {
        uint32_t p = u2[(long)edata[s0 + k] * 64 + lane];
        fx += bf16_lo(p); fy += bf16_hi(p);
    }
    k = 0;
    for (; k + 4 <= d1; k += 4) {
        int c0 = edata[s1 + k], c1 = edata[s1 + k + 1];
        int c2 = edata[s1 + k + 2], c3 = edata[s1 + k + 3];
        uint32_t p0 = v2[(long)c0 * 64 + lane];
        uint32_t p1 = v2[(long)c1 * 64 + lane];
        uint32_t p2 = v2[(long)c2 * 64 + lane];
        uint32_t p3 = v2[(long)c3 * 64 + lane];
        bx += bf16_lo(p0) + bf16_lo(p1) + bf16_lo(p2) + bf16_lo(p3);
        by += bf16_hi(p0) + bf16_hi(p1) + bf16_hi(p2) + bf16_hi(p3);
    }
    for (; k < d1; ++k) {
        uint32_t p = v2[(long)edata[s1 + k] * 64 + lane];
        bx += bf16_lo(p); by += bf16_hi(p);
    }

    float io = inv_out[node], ii = inv_in[node];
    float2 b = bias2[lane];
    out2[(long)node * 64 + lane] =
        make_float2(io * fx + ii * bx + b.x, io * fy + ii * by + b.y);
}

extern "C" void kernel_launch(void* const* d_in, const int* in_sizes, int n_in,
                              void* d_out, int out_size, void* d_ws, size_t ws_size,
                              hipStream_t stream) {
    const int N = in_sizes[0] / D;    // 100000
    const int E = in_sizes[1] / 2;    // 1600000
    const int nbuk = (N + 255) >> 8;  // 391 coarse buckets per direction
    const int nb2 = 2 * nbuk;         // 782  (<= 1024 for LDS arrays)

    const float* x    = (const float*)d_in[0];
    const int*   ei   = (const int*)d_in[1];
    const float* Wsrc = (const float*)d_in[2];
    const float* bsrc = (const float*)d_in[3];
    const float* Wdst = (const float*)d_in[4];
    const float* bdst = (const float*)d_in[5];

    char* ws = (char*)d_ws;
    size_t off = 0;
    uint32_t* gcount = (uint32_t*)(ws + off); off += 1024 * 4;   // zeroed
    uint32_t* pbase  = (uint32_t*)(ws + off); off += 1024 * 4;
    uint32_t* gcur   = (uint32_t*)(ws + off); off += 1024 * 4;
    float*    inv_o  = (float*)(ws + off);    off += (size_t)N * 4;
    float*    inv_i  = (float*)(ws + off);    off += (size_t)N * 4;
    float*    biasc  = (float*)(ws + off);    off += 128 * 4;
    uint16_t* WtS    = (uint16_t*)(ws + off); off += (size_t)D * D * 2;
    uint16_t* WtD    = (uint16_t*)(ws + off); off += (size_t)D * D * 2;
    uint32_t* ptrg   = (uint32_t*)(ws + off); off += (size_t)2 * N * 4;
    uint32_t* degg   = (uint32_t*)(ws + off); off += (size_t)2 * N * 4;
    uint32_t* gpairs = (uint32_t*)(ws + off); off += (size_t)2 * E * 4;
    int*      edata  = (int*)(ws + off);      off += (size_t)2 * E * 4;
    uint32_t* u2     = (uint32_t*)(ws + off); off += (size_t)N * 64 * 4;
    uint32_t* v2     = (uint32_t*)(ws + off); off += (size_t)N * 64 * 4;

    hipMemsetAsync(gcount, 0, 1024 * 4, stream);

    k_prep_w<<<128, 256, 0, stream>>>(Wsrc, bsrc, Wdst, bdst, WtS, WtD, biasc);
    k_count<<<(E + CC - 1) / CC, 256, 0, stream>>>(ei, E, nbuk, gcount);
    k_bases<<<1, 256, 0, stream>>>(gcount, pbase, gcur, nb2);
    k_part<<<(E + CE - 1) / CE, 256, 0, stream>>>(ei, E, nbuk, gcur, gpairs);
    k_build<<<nb2, 256, 0, stream>>>(gpairs, pbase, gcount, nbuk, N,
                                     edata, ptrg, degg, inv_o, inv_i);

    int npairs = (N + 1) / 2;
    k_uv<<<1024, 256, 0, stream>>>(x, WtS, WtD, inv_o, inv_i, u2, v2, N, npairs);

    k_gather<<<(N + 3) / 4, 256, 0, stream>>>(u2, v2, edata, ptrg, degg,
                                              inv_o, inv_i, (const float2*)biasc,
                                              (float2*)d_out, N);
}

// Round 5
// 358.943 us; speedup vs baseline: 8.4404x; 1.3528x over previous
//
#include <hip/hip_runtime.h>
#include <stdint.h>

#define D 128
#define CC 4096   // edges per k_count block
#define CE 2048   // edges per k_part block (4096 entries in LDS)

typedef __attribute__((ext_vector_type(8))) __bf16 bf16x8;
typedef __attribute__((ext_vector_type(4))) float floatx4;

union FragU { uint4 u; bf16x8 b; };

__device__ __forceinline__ float bf16_lo(uint32_t u) { return __uint_as_float(u << 16); }
__device__ __forceinline__ float bf16_hi(uint32_t u) { return __uint_as_float(u & 0xffff0000u); }
__device__ __forceinline__ uint16_t f32_to_bf16(float f) {
    uint32_t u = __float_as_uint(f);
    uint32_t r = u + 0x7fffu + ((u >> 16) & 1u);  // round-to-nearest-even
    return (uint16_t)(r >> 16);
}
__device__ __forceinline__ uint32_t pack2(float a, float b) {
    return (uint32_t)f32_to_bf16(a) | ((uint32_t)f32_to_bf16(b) << 16);
}

// WcatT[o][i]: rows 0..127 = bf16(0.5*W_src[o][i]), rows 128..255 = bf16(0.5*W_dst)
// (this [N_out][K] layout is directly the MFMA B-fragment source, j-contiguous in K)
__global__ __launch_bounds__(256) void k_prep_w(
    const float* __restrict__ Wsrc, const float* __restrict__ bsrc,
    const float* __restrict__ Wdst, const float* __restrict__ bdst,
    uint16_t* __restrict__ WcatT, float* __restrict__ bias)
{
    int t = blockIdx.x * 256 + threadIdx.x;  // 0..32767
    if (t < 16384) {
        WcatT[t] = f32_to_bf16(0.5f * Wsrc[t]);
        if (t < 128) bias[t] = 0.5f * (bsrc[t] + bdst[t]);
    } else {
        WcatT[t] = f32_to_bf16(0.5f * Wdst[t - 16384]);
    }
}

// Coarse bucket counts. bucket = node>>8; fwd buckets [0,nbuk), bwd [nbuk,2*nbuk)
__global__ __launch_bounds__(256) void k_count(
    const int* __restrict__ ei, int E, int nbuk, uint32_t* __restrict__ gcount)
{
    __shared__ uint32_t cnt[1024];
    int nb2 = 2 * nbuk;
    for (int j = threadIdx.x; j < nb2; j += 256) cnt[j] = 0;
    __syncthreads();
    int base = blockIdx.x * CC;
    int lim = min(CC, E - base);
    for (int i = threadIdx.x; i < lim; i += 256) {
        int r = ei[base + i];
        int c = ei[E + base + i];
        atomicAdd(&cnt[r >> 8], 1u);
        atomicAdd(&cnt[nbuk + (c >> 8)], 1u);
    }
    __syncthreads();
    for (int j = threadIdx.x; j < nb2; j += 256) {
        uint32_t v = cnt[j];
        if (v) atomicAdd(&gcount[j], v);
    }
}

// Exclusive scan of gcount[0..nb2) -> pbase; gcursor = copy (mutable)
__global__ __launch_bounds__(256) void k_bases(
    const uint32_t* __restrict__ gcount, uint32_t* __restrict__ pbase,
    uint32_t* __restrict__ gcursor, int nb2)
{
    __shared__ uint32_t s[256];
    uint32_t v[4]; uint32_t tsum = 0;
    int b0 = threadIdx.x * 4;
    #pragma unroll
    for (int j = 0; j < 4; ++j) { v[j] = (b0 + j < nb2) ? gcount[b0 + j] : 0u; tsum += v[j]; }
    s[threadIdx.x] = tsum;
    __syncthreads();
    for (int off = 1; off < 256; off <<= 1) {
        uint32_t t = (threadIdx.x >= (unsigned)off) ? s[threadIdx.x - off] : 0u;
        __syncthreads();
        s[threadIdx.x] += t;
        __syncthreads();
    }
    uint32_t run = s[threadIdx.x] - tsum;
    #pragma unroll
    for (int j = 0; j < 4; ++j) {
        if (b0 + j < nb2) { pbase[b0 + j] = run; gcursor[b0 + j] = run; }
        run += v[j];
    }
}

// Partition: block counting-sorts its 2048 edges (x2 dirs) by coarse bucket in LDS,
// reserves per-bucket global runs, streams bucket-sorted entries out (coalesced).
// Entry pack: (payload << 8) | (key & 255)
__global__ __launch_bounds__(256) void k_part(
    const int* __restrict__ ei, int E, int nbuk,
    uint32_t* __restrict__ gcursor, uint32_t* __restrict__ gpairs)
{
    __shared__ uint32_t cnt[1024];
    __shared__ uint32_t loff[1024];
    __shared__ uint32_t gbase[1024];
    __shared__ uint32_t spair[2 * CE];
    __shared__ uint16_t sbid[2 * CE];
    __shared__ uint32_t ssum[256];
    int nb2 = 2 * nbuk;
    for (int j = threadIdx.x; j < nb2; j += 256) cnt[j] = 0;
    __syncthreads();
    int base = blockIdx.x * CE;
    int lim = min(CE, E - base);
    for (int i = threadIdx.x; i < lim; i += 256) {
        int r = ei[base + i];
        int c = ei[E + base + i];
        atomicAdd(&cnt[r >> 8], 1u);
        atomicAdd(&cnt[nbuk + (c >> 8)], 1u);
    }
    __syncthreads();
    uint32_t v0 = 0, v1 = 0, v2 = 0, v3 = 0;
    int b0 = threadIdx.x * 4;
    if (b0 < nb2)     v0 = cnt[b0];
    if (b0 + 1 < nb2) v1 = cnt[b0 + 1];
    if (b0 + 2 < nb2) v2 = cnt[b0 + 2];
    if (b0 + 3 < nb2) v3 = cnt[b0 + 3];
    uint32_t tsum = v0 + v1 + v2 + v3;
    ssum[threadIdx.x] = tsum;
    __syncthreads();
    for (int off = 1; off < 256; off <<= 1) {
        uint32_t t = (threadIdx.x >= (unsigned)off) ? ssum[threadIdx.x - off] : 0u;
        __syncthreads();
        ssum[threadIdx.x] += t;
        __syncthreads();
    }
    uint32_t run = ssum[threadIdx.x] - tsum;
    if (b0 < nb2)     loff[b0]     = run;
    if (b0 + 1 < nb2) loff[b0 + 1] = run + v0;
    if (b0 + 2 < nb2) loff[b0 + 2] = run + v0 + v1;
    if (b0 + 3 < nb2) loff[b0 + 3] = run + v0 + v1 + v2;
    __syncthreads();
    for (int j = threadIdx.x; j < nb2; j += 256) {
        uint32_t c2 = cnt[j];
        gbase[j] = c2 ? atomicAdd(&gcursor[j], c2) : 0u;
        cnt[j] = loff[j];
    }
    __syncthreads();
    for (int i = threadIdx.x; i < lim; i += 256) {
        int r = ei[base + i];
        int c = ei[E + base + i];
        int bf = r >> 8;
        uint32_t sf = atomicAdd(&cnt[bf], 1u);
        spair[sf] = ((uint32_t)c << 8) | (uint32_t)(r & 255);
        sbid[sf] = (uint16_t)bf;
        int bb = nbuk + (c >> 8);
        uint32_t sb = atomicAdd(&cnt[bb], 1u);
        spair[sb] = ((uint32_t)r << 8) | (uint32_t)(c & 255);
        sbid[sb] = (uint16_t)bb;
    }
    __syncthreads();
    int total = 2 * lim;
    for (int s2 = threadIdx.x; s2 < total; s2 += 256) {
        int b = sbid[s2];
        gpairs[gbase[b] + ((uint32_t)s2 - loff[b])] = spair[s2];
    }
}

// Fine build: one block per (dir,bucket): 256-key histogram, scan, write ptr/deg/inv,
// scatter payloads into the bucket's L2-hot edata region.
__global__ __launch_bounds__(256) void k_build(
    const uint32_t* __restrict__ gpairs, const uint32_t* __restrict__ pbase,
    const uint32_t* __restrict__ gcount, int nbuk, int N,
    int* __restrict__ edata, uint32_t* __restrict__ ptrg, uint32_t* __restrict__ degg,
    float* __restrict__ inv_o, float* __restrict__ inv_i)
{
    __shared__ uint32_t hist[256], cur[256], ssum[256];
    int b = blockIdx.x;
    int dir = (b >= nbuk) ? 1 : 0;
    int node0 = (b - dir * nbuk) << 8;
    uint32_t base = pbase[b];
    uint32_t cnt_b = gcount[b];
    hist[threadIdx.x] = 0;
    __syncthreads();
    for (uint32_t i = threadIdx.x; i < cnt_b; i += 256)
        atomicAdd(&hist[gpairs[base + i] & 255u], 1u);
    __syncthreads();
    uint32_t h = hist[threadIdx.x];
    ssum[threadIdx.x] = h;
    __syncthreads();
    for (int off = 1; off < 256; off <<= 1) {
        uint32_t t = (threadIdx.x >= (unsigned)off) ? ssum[threadIdx.x - off] : 0u;
        __syncthreads();
        ssum[threadIdx.x] += t;
        __syncthreads();
    }
    uint32_t excl = ssum[threadIdx.x] - h;
    cur[threadIdx.x] = excl;
    int n = node0 + threadIdx.x;
    if (n < N) {
        ptrg[dir * N + n] = base + excl;
        degg[dir * N + n] = h;
        float iv = h ? rsqrtf((float)h) : 0.0f;
        if (dir == 0) inv_o[n] = iv; else inv_i[n] = iv;
    }
    __syncthreads();
    for (uint32_t i = threadIdx.x; i < cnt_b; i += 256) {
        uint32_t e = gpairs[base + i];
        uint32_t pos = atomicAdd(&cur[e & 255u], 1u);
        edata[base + pos] = (int)(e >> 8);
    }
}

// MFMA projection: mat = blockIdx&1 (0: u = inv_in.(x@0.5Ws^T), 1: v = inv_out.(x@0.5Wd^T))
// 16x16x32 bf16 MFMA; B-fragments (8 col-tiles x 4 K-steps) held in VGPRs for the
// whole kernel; A converted fp32->bf16 (RNE) in flight; bf16 scalar stores.
__global__ __launch_bounds__(256, 2) void k_mm(
    const float* __restrict__ x, const uint4* __restrict__ Wt4,
    const float* __restrict__ inv_o, const float* __restrict__ inv_i,
    uint16_t* __restrict__ u2b, uint16_t* __restrict__ v2b, int N)
{
    const int lane = threadIdx.x & 63;
    const int m16 = lane & 15;      // A row / B col / D col within tile
    const int quad = lane >> 4;     // 0..3
    const int mat = blockIdx.x & 1;
    uint16_t* outb = mat ? v2b : u2b;
    const float* inv = mat ? inv_o : inv_i;

    // B fragments: lane holds B[k = ks*32 + quad*8 + j][n = ct*16 + m16], j=0..7
    // source WcatT row-major [256][128] -> 16B contiguous per fragment
    bf16x8 Bf[8][4];
    #pragma unroll
    for (int ct = 0; ct < 8; ++ct) {
        #pragma unroll
        for (int ks = 0; ks < 4; ++ks) {
            int n = mat * 128 + ct * 16 + m16;
            FragU f; f.u = Wt4[n * 16 + ks * 4 + quad];
            Bf[ct][ks] = f.b;
        }
    }

    const int ntiles = (N + 15) >> 4;
    const int wslot = (blockIdx.x >> 1) * 4 + (threadIdx.x >> 6);
    const int nslot = (gridDim.x >> 1) * 4;

    for (int t = wslot; t < ntiles; t += nslot) {
        int rowA = t * 16 + m16;
        if (rowA >= N) rowA = N - 1;
        const float4* xr = (const float4*)(x + (long)rowA * 128);
        bf16x8 Af[4];   // lane holds A[m16][k = ks*32 + quad*8 + j]
        #pragma unroll
        for (int ks = 0; ks < 4; ++ks) {
            float4 p0 = xr[ks * 8 + quad * 2];
            float4 p1 = xr[ks * 8 + quad * 2 + 1];
            FragU f;
            f.u.x = pack2(p0.x, p0.y);
            f.u.y = pack2(p0.z, p0.w);
            f.u.z = pack2(p1.x, p1.y);
            f.u.w = pack2(p1.z, p1.w);
            Af[ks] = f.b;
        }
        float iv[4];
        #pragma unroll
        for (int r = 0; r < 4; ++r) {
            int row = t * 16 + quad * 4 + r;
            iv[r] = inv[row < N ? row : 0];
        }
        #pragma unroll
        for (int ct = 0; ct < 8; ++ct) {
            floatx4 acc = {};
            #pragma unroll
            for (int ks = 0; ks < 4; ++ks)
                acc = __builtin_amdgcn_mfma_f32_16x16x32_bf16(Af[ks], Bf[ct][ks], acc, 0, 0, 0);
            // D: col = m16 (within ct tile), row = quad*4 + r
            #pragma unroll
            for (int r = 0; r < 4; ++r) {
                int row = t * 16 + quad * 4 + r;
                if (row < N)
                    outb[(long)row * 128 + ct * 16 + m16] = f32_to_bf16(acc[r] * iv[r]);
            }
        }
    }
}

// One wave per node: out[n] = inv_out[n]*sum(u[CSR cols]) + inv_in[n]*sum(v[CSC rows]) + bias
__global__ __launch_bounds__(256) void k_gather(
    const uint32_t* __restrict__ u2, const uint32_t* __restrict__ v2,
    const int* __restrict__ edata,
    const uint32_t* __restrict__ ptrg, const uint32_t* __restrict__ degg,
    const float* __restrict__ inv_out, const float* __restrict__ inv_in,
    const float2* __restrict__ bias2, float2* __restrict__ out2, int N)
{
    int lane = threadIdx.x & 63;
    int node = blockIdx.x * 4 + (threadIdx.x >> 6);
    if (node >= N) return;

    uint32_t s0 = ptrg[node],     d0 = degg[node];
    uint32_t s1 = ptrg[N + node], d1 = degg[N + node];

    float fx = 0, fy = 0, bx = 0, by = 0;
    uint32_t k = 0;
    for (; k + 4 <= d0; k += 4) {
        int c0 = edata[s0 + k], c1 = edata[s0 + k + 1];
        int c2 = edata[s0 + k + 2], c3 = edata[s0 + k + 3];
        uint32_t p0 = u2[(long)c0 * 64 + lane];
        uint32_t p1 = u2[(long)c1 * 64 + lane];
        uint32_t p2 = u2[(long)c2 * 64 + lane];
        uint32_t p3 = u2[(long)c3 * 64 + lane];
        fx += bf16_lo(p0) + bf16_lo(p1) + bf16_lo(p2) + bf16_lo(p3);
        fy += bf16_hi(p0) + bf16_hi(p1) + bf16_hi(p2) + bf16_hi(p3);
    }
    for (; k < d0; ++k) {
        uint32_t p = u2[(long)edata[s0 + k] * 64 + lane];
        fx += bf16_lo(p); fy += bf16_hi(p);
    }
    k = 0;
    for (; k + 4 <= d1; k += 4) {
        int c0 = edata[s1 + k], c1 = edata[s1 + k + 1];
        int c2 = edata[s1 + k + 2], c3 = edata[s1 + k + 3];
        uint32_t p0 = v2[(long)c0 * 64 + lane];
        uint32_t p1 = v2[(long)c1 * 64 + lane];
        uint32_t p2 = v2[(long)c2 * 64 + lane];
        uint32_t p3 = v2[(long)c3 * 64 + lane];
        bx += bf16_lo(p0) + bf16_lo(p1) + bf16_lo(p2) + bf16_lo(p3);
        by += bf16_hi(p0) + bf16_hi(p1) + bf16_hi(p2) + bf16_hi(p3);
    }
    for (; k < d1; ++k) {
        uint32_t p = v2[(long)edata[s1 + k] * 64 + lane];
        bx += bf16_lo(p); by += bf16_hi(p);
    }

    float io = inv_out[node], ii = inv_in[node];
    float2 b = bias2[lane];
    out2[(long)node * 64 + lane] =
        make_float2(io * fx + ii * bx + b.x, io * fy + ii * by + b.y);
}

extern "C" void kernel_launch(void* const* d_in, const int* in_sizes, int n_in,
                              void* d_out, int out_size, void* d_ws, size_t ws_size,
                              hipStream_t stream) {
    const int N = in_sizes[0] / D;    // 100000
    const int E = in_sizes[1] / 2;    // 1600000
    const int nbuk = (N + 255) >> 8;  // 391 coarse buckets per direction
    const int nb2 = 2 * nbuk;         // 782

    const float* x    = (const float*)d_in[0];
    const int*   ei   = (const int*)d_in[1];
    const float* Wsrc = (const float*)d_in[2];
    const float* bsrc = (const float*)d_in[3];
    const float* Wdst = (const float*)d_in[4];
    const float* bdst = (const float*)d_in[5];

    char* ws = (char*)d_ws;
    size_t off = 0;
    uint32_t* gcount = (uint32_t*)(ws + off); off += 1024 * 4;   // zeroed
    uint32_t* pbase  = (uint32_t*)(ws + off); off += 1024 * 4;
    uint32_t* gcur   = (uint32_t*)(ws + off); off += 1024 * 4;
    float*    inv_o  = (float*)(ws + off);    off += (size_t)N * 4;
    float*    inv_i  = (float*)(ws + off);    off += (size_t)N * 4;
    float*    biasc  = (float*)(ws + off);    off += 128 * 4;
    uint16_t* WcatT  = (uint16_t*)(ws + off); off += (size_t)256 * 128 * 2;
    uint32_t* ptrg   = (uint32_t*)(ws + off); off += (size_t)2 * N * 4;
    uint32_t* degg   = (uint32_t*)(ws + off); off += (size_t)2 * N * 4;
    uint32_t* gpairs = (uint32_t*)(ws + off); off += (size_t)2 * E * 4;
    int*      edata  = (int*)(ws + off);      off += (size_t)2 * E * 4;
    uint32_t* u2     = (uint32_t*)(ws + off); off += (size_t)N * 64 * 4;
    uint32_t* v2     = (uint32_t*)(ws + off); off += (size_t)N * 64 * 4;

    hipMemsetAsync(gcount, 0, 1024 * 4, stream);

    k_prep_w<<<128, 256, 0, stream>>>(Wsrc, bsrc, Wdst, bdst, WcatT, biasc);
    k_count<<<(E + CC - 1) / CC, 256, 0, stream>>>(ei, E, nbuk, gcount);
    k_bases<<<1, 256, 0, stream>>>(gcount, pbase, gcur, nb2);
    k_part<<<(E + CE - 1) / CE, 256, 0, stream>>>(ei, E, nbuk, gcur, gpairs);
    k_build<<<nb2, 256, 0, stream>>>(gpairs, pbase, gcount, nbuk, N,
                                     edata, ptrg, degg, inv_o, inv_i);

    k_mm<<<1024, 256, 0, stream>>>(x, (const uint4*)WcatT, inv_o, inv_i,
                                   (uint16_t*)u2, (uint16_t*)v2, N);

    k_gather<<<(N + 3) / 4, 256, 0, stream>>>(u2, v2, edata, ptrg, degg,
                                              inv_o, inv_i, (const float2*)biasc,
                                              (float2*)d_out, N);
}